// Round 6
// baseline (19.637 us; speedup 1.0000x reference)
//
#include <hip/hip_runtime.h>
#include <math.h>

#define THREADS 256
#define PTS 4  // test points per block (2 f32x2 pairs)

typedef __attribute__((ext_vector_type(2))) float f32x2;

// Single fused kernel: block b owns test points [4b, 4b+4); each thread
// streams a stride-256 slice of ALL train rows (L2-resident, coalesced),
// accumulating 4 partial sums; LDS+shuffle block reduce writes out[].
// Math: exp(-||x-y||^2/(2 var)) = exp2(a + b_j + dot(2k*x, y)),
// a = -k||x||^2, b_j = -k||y_j||^2, k = log2(e)/(2 var).
// Point-pairs are processed as f32x2 lanes to allow v_pk_fma_f32 formation.
__global__ __launch_bounds__(THREADS) void kde_fused(
    const float* __restrict__ test, const float* __restrict__ train,
    float* __restrict__ out, int M, int N, float negk, float twok,
    float scale) {
  __shared__ float lds[PTS][THREADS];

  const int t = threadIdx.x;
  const int mbase = blockIdx.x * PTS;

  // xs[q][d] = {x[2q][d], x[2q+1][d]} * 2k ; aseed[q] = {a[2q], a[2q+1]}
  f32x2 xs[PTS / 2][8];
  f32x2 aseed[PTS / 2], acc2[PTS / 2];
#pragma unroll
  for (int q = 0; q < PTS / 2; ++q) {
    float xr[2][8];
    float av[2];
#pragma unroll
    for (int h = 0; h < 2; ++h) {
      const float4* xp = reinterpret_cast<const float4*>(test) +
                         (size_t)min(mbase + 2 * q + h, M - 1) * 2;
      float4 u = xp[0], v = xp[1];
      av[h] = negk * (u.x * u.x + u.y * u.y + u.z * u.z + u.w * u.w +
                      v.x * v.x + v.y * v.y + v.z * v.z + v.w * v.w);
      xr[h][0] = u.x * twok; xr[h][1] = u.y * twok;
      xr[h][2] = u.z * twok; xr[h][3] = u.w * twok;
      xr[h][4] = v.x * twok; xr[h][5] = v.y * twok;
      xr[h][6] = v.z * twok; xr[h][7] = v.w * twok;
    }
#pragma unroll
    for (int d = 0; d < 8; ++d) xs[q][d] = (f32x2){xr[0][d], xr[1][d]};
    aseed[q] = (f32x2){av[0], av[1]};
    acc2[q] = (f32x2){0.f, 0.f};
  }

  const float4* tp = reinterpret_cast<const float4*>(train);
#pragma unroll 2
  for (int r = t; r < N; r += THREADS) {
    float4 y0 = tp[(size_t)r * 2];
    float4 y1 = tp[(size_t)r * 2 + 1];
    float b = negk * (y0.x * y0.x + y0.y * y0.y + y0.z * y0.z + y0.w * y0.w +
                      y1.x * y1.x + y1.y * y1.y + y1.z * y1.z + y1.w * y1.w);
    f32x2 bb = {b, b};
#pragma unroll
    for (int q = 0; q < PTS / 2; ++q) {
      f32x2 g = aseed[q] + bb;
      g += xs[q][0] * (f32x2){y0.x, y0.x};
      g += xs[q][1] * (f32x2){y0.y, y0.y};
      g += xs[q][2] * (f32x2){y0.z, y0.z};
      g += xs[q][3] * (f32x2){y0.w, y0.w};
      g += xs[q][4] * (f32x2){y1.x, y1.x};
      g += xs[q][5] * (f32x2){y1.y, y1.y};
      g += xs[q][6] * (f32x2){y1.z, y1.z};
      g += xs[q][7] * (f32x2){y1.w, y1.w};
      acc2[q].x += __builtin_amdgcn_exp2f(g.x);
      acc2[q].y += __builtin_amdgcn_exp2f(g.y);
    }
  }

  // Block reduce: 256 partials -> 1 per point (fixed order, deterministic).
#pragma unroll
  for (int q = 0; q < PTS / 2; ++q) {
    lds[2 * q][t] = acc2[q].x;
    lds[2 * q + 1][t] = acc2[q].y;
  }
  __syncthreads();
  const int w = t >> 6;    // wave id 0..3 handles point p = w
  const int lane = t & 63;
  {
    const int p = w;
    float s = lds[p][lane] + lds[p][lane + 64] + lds[p][lane + 128] +
              lds[p][lane + 192];
#pragma unroll
    for (int off = 32; off > 0; off >>= 1) s += __shfl_down(s, off);
    if (lane == 0) {
      int m = mbase + p;
      if (m < M) out[m] = scale * s;
    }
  }
}

extern "C" void kernel_launch(void* const* d_in, const int* in_sizes, int n_in,
                              void* d_out, int out_size, void* d_ws,
                              size_t ws_size, hipStream_t stream) {
  const float* test = (const float*)d_in[0];
  const float* train = (const float*)d_in[1];
  float* out = (float*)d_out;
  int M = in_sizes[0] / 8;
  int N = in_sizes[1] / 8;

  const double var = 0.05 * 0.05;
  const double k = 1.4426950408889634 / (2.0 * var);  // log2(e)/(2 var)
  const float negk = (float)(-k);
  const float twok = (float)(2.0 * k);
  const float coef = (float)(1.0 / sqrt(2.0 * M_PI * var));
  const float scale = coef / (float)N;

  int nblocks = (M + PTS - 1) / PTS;
  kde_fused<<<nblocks, THREADS, 0, stream>>>(test, train, out, M, N, negk,
                                             twok, scale);
}

// Round 7
// 17.655 us; speedup vs baseline: 1.1123x; 1.1123x over previous
//
#include <hip/hip_runtime.h>
#include <math.h>

#define THREADS 256
#define PTS 8  // test points per block, processed as 4 packed point-pairs

typedef float f32x2 __attribute__((ext_vector_type(2)));

// Single fused kernel: block b owns test points [8b, 8b+8); each thread
// streams a stride-256 slice of ALL train rows (each train byte read exactly
// once per block -> 512*256KB = 128MB total L2 traffic), accumulating 8
// partial sums; LDS+shuffle block reduce writes out[].
// Math: exp(-||x-y||^2/(2 var)) = exp2(a + b_j + dot(2k*x, y)),
// a = -k||x||^2, b_j = -k||y_j||^2, k = log2(e)/(2 var).
// Point-pairs packed as f32x2 with __builtin_elementwise_fma to form
// v_pk_fma_f32 (CDNA2+ packed dual fp32 FMA).
__global__ __launch_bounds__(THREADS) void kde_fused(
    const float* __restrict__ test, const float* __restrict__ train,
    float* __restrict__ out, int M, int N, float negk, float twok,
    float scale) {
  __shared__ float lds[PTS][THREADS];

  const int t = threadIdx.x;
  const int mbase = blockIdx.x * PTS;

  // xs[q][d] = {x[2q][d], x[2q+1][d]} * 2k ; aseed[q] = {a[2q], a[2q+1]}
  f32x2 xs[PTS / 2][8];
  f32x2 aseed[PTS / 2], acc2[PTS / 2];
#pragma unroll
  for (int q = 0; q < PTS / 2; ++q) {
    float xr[2][8];
    float av[2];
#pragma unroll
    for (int h = 0; h < 2; ++h) {
      const float4* xp = reinterpret_cast<const float4*>(test) +
                         (size_t)min(mbase + 2 * q + h, M - 1) * 2;
      float4 u = xp[0], v = xp[1];
      av[h] = negk * (u.x * u.x + u.y * u.y + u.z * u.z + u.w * u.w +
                      v.x * v.x + v.y * v.y + v.z * v.z + v.w * v.w);
      xr[h][0] = u.x * twok; xr[h][1] = u.y * twok;
      xr[h][2] = u.z * twok; xr[h][3] = u.w * twok;
      xr[h][4] = v.x * twok; xr[h][5] = v.y * twok;
      xr[h][6] = v.z * twok; xr[h][7] = v.w * twok;
    }
#pragma unroll
    for (int d = 0; d < 8; ++d) xs[q][d] = (f32x2){xr[0][d], xr[1][d]};
    aseed[q] = (f32x2){av[0], av[1]};
    acc2[q] = (f32x2){0.f, 0.f};
  }

  const float4* tp = reinterpret_cast<const float4*>(train);
#pragma unroll 2
  for (int r = t; r < N; r += THREADS) {
    float4 y0 = tp[(size_t)r * 2];
    float4 y1 = tp[(size_t)r * 2 + 1];
    float b = negk * (y0.x * y0.x + y0.y * y0.y + y0.z * y0.z + y0.w * y0.w +
                      y1.x * y1.x + y1.y * y1.y + y1.z * y1.z + y1.w * y1.w);
    const f32x2 bb = {b, b};
    const f32x2 yb[8] = {{y0.x, y0.x}, {y0.y, y0.y}, {y0.z, y0.z},
                         {y0.w, y0.w}, {y1.x, y1.x}, {y1.y, y1.y},
                         {y1.z, y1.z}, {y1.w, y1.w}};
#pragma unroll
    for (int q = 0; q < PTS / 2; ++q) {
      f32x2 g = aseed[q] + bb;
#pragma unroll
      for (int d = 0; d < 8; ++d) g = __builtin_elementwise_fma(xs[q][d], yb[d], g);
      f32x2 e = {__builtin_amdgcn_exp2f(g.x), __builtin_amdgcn_exp2f(g.y)};
      acc2[q] += e;
    }
  }

  // Block reduce: 256 partials -> 1 per point (fixed order, deterministic).
#pragma unroll
  for (int q = 0; q < PTS / 2; ++q) {
    lds[2 * q][t] = acc2[q].x;
    lds[2 * q + 1][t] = acc2[q].y;
  }
  __syncthreads();
  const int w = t >> 6;
  const int lane = t & 63;
  for (int p = w; p < PTS; p += THREADS / 64) {
    float s = lds[p][lane] + lds[p][lane + 64] + lds[p][lane + 128] +
              lds[p][lane + 192];
#pragma unroll
    for (int off = 32; off > 0; off >>= 1) s += __shfl_down(s, off);
    if (lane == 0) {
      int m = mbase + p;
      if (m < M) out[m] = scale * s;
    }
  }
}

extern "C" void kernel_launch(void* const* d_in, const int* in_sizes, int n_in,
                              void* d_out, int out_size, void* d_ws,
                              size_t ws_size, hipStream_t stream) {
  const float* test = (const float*)d_in[0];
  const float* train = (const float*)d_in[1];
  float* out = (float*)d_out;
  int M = in_sizes[0] / 8;
  int N = in_sizes[1] / 8;

  const double var = 0.05 * 0.05;
  const double k = 1.4426950408889634 / (2.0 * var);  // log2(e)/(2 var)
  const float negk = (float)(-k);
  const float twok = (float)(2.0 * k);
  const float coef = (float)(1.0 / sqrt(2.0 * M_PI * var));
  const float scale = coef / (float)N;

  int nblocks = (M + PTS - 1) / PTS;
  kde_fused<<<nblocks, THREADS, 0, stream>>>(test, train, out, M, N, negk,
                                             twok, scale);
}

// Round 8
// 16.687 us; speedup vs baseline: 1.1768x; 1.0580x over previous
//
#include <hip/hip_runtime.h>
#include <math.h>

#define THREADS 512
#define PTS 16  // test points per block, processed as 8 packed point-pairs

typedef float f32x2 __attribute__((ext_vector_type(2)));

// Single fused kernel: block b owns test points [16b, 16b+16); each thread
// streams a stride-512 slice of ALL train rows (256 blocks x 256KB = 64MB
// total L2 traffic), accumulating 16 partial sums; LDS block reduce -> out[].
// Math: exp(-||x-y||^2/(2 var)) = exp2(a + b_j + dot(2k*x, y)),
// a = -k||x||^2, b_j = -k||y_j||^2, k = log2(e)/(2 var).
// Point-pairs packed as f32x2 + __builtin_elementwise_fma -> v_pk_fma_f32.
__global__ __launch_bounds__(THREADS, 2) void kde_fused(
    const float* __restrict__ test, const float* __restrict__ train,
    float* __restrict__ out, int M, int N, float negk, float twok,
    float scale) {
  __shared__ float lds[PTS][THREADS];

  const int t = threadIdx.x;
  const int mbase = blockIdx.x * PTS;

  // xs[q][d] = {x[2q][d], x[2q+1][d]} * 2k ; aseed[q] = {a[2q], a[2q+1]}
  f32x2 xs[PTS / 2][8];
  f32x2 aseed[PTS / 2], acc2[PTS / 2];
#pragma unroll
  for (int q = 0; q < PTS / 2; ++q) {
    float xr[2][8];
    float av[2];
#pragma unroll
    for (int h = 0; h < 2; ++h) {
      const float4* xp = reinterpret_cast<const float4*>(test) +
                         (size_t)min(mbase + 2 * q + h, M - 1) * 2;
      float4 u = xp[0], v = xp[1];
      av[h] = negk * (u.x * u.x + u.y * u.y + u.z * u.z + u.w * u.w +
                      v.x * v.x + v.y * v.y + v.z * v.z + v.w * v.w);
      xr[h][0] = u.x * twok; xr[h][1] = u.y * twok;
      xr[h][2] = u.z * twok; xr[h][3] = u.w * twok;
      xr[h][4] = v.x * twok; xr[h][5] = v.y * twok;
      xr[h][6] = v.z * twok; xr[h][7] = v.w * twok;
    }
#pragma unroll
    for (int d = 0; d < 8; ++d) xs[q][d] = (f32x2){xr[0][d], xr[1][d]};
    aseed[q] = (f32x2){av[0], av[1]};
    acc2[q] = (f32x2){0.f, 0.f};
  }

  const float4* tp = reinterpret_cast<const float4*>(train);
#pragma unroll 2
  for (int r = t; r < N; r += THREADS) {
    float4 y0 = tp[(size_t)r * 2];
    float4 y1 = tp[(size_t)r * 2 + 1];
    float b = negk * (y0.x * y0.x + y0.y * y0.y + y0.z * y0.z + y0.w * y0.w +
                      y1.x * y1.x + y1.y * y1.y + y1.z * y1.z + y1.w * y1.w);
    const f32x2 bb = {b, b};
    const f32x2 yb[8] = {{y0.x, y0.x}, {y0.y, y0.y}, {y0.z, y0.z},
                         {y0.w, y0.w}, {y1.x, y1.x}, {y1.y, y1.y},
                         {y1.z, y1.z}, {y1.w, y1.w}};
#pragma unroll
    for (int q = 0; q < PTS / 2; ++q) {
      f32x2 g = aseed[q] + bb;
#pragma unroll
      for (int d = 0; d < 8; ++d)
        g = __builtin_elementwise_fma(xs[q][d], yb[d], g);
      f32x2 e = {__builtin_amdgcn_exp2f(g.x), __builtin_amdgcn_exp2f(g.y)};
      acc2[q] += e;
    }
  }

  // Block reduce: 512 partials -> 1 per point (fixed order, deterministic).
#pragma unroll
  for (int q = 0; q < PTS / 2; ++q) {
    lds[2 * q][t] = acc2[q].x;
    lds[2 * q + 1][t] = acc2[q].y;
  }
  __syncthreads();
  const int w = t >> 6;  // 8 waves; wave w reduces points w and w+8
  const int lane = t & 63;
#pragma unroll
  for (int pp = 0; pp < PTS / 8; ++pp) {
    const int p = w + pp * 8;
    float s = 0.f;
#pragma unroll
    for (int seg = 0; seg < THREADS / 64; ++seg) s += lds[p][lane + seg * 64];
#pragma unroll
    for (int off = 32; off > 0; off >>= 1) s += __shfl_down(s, off);
    if (lane == 0) {
      int m = mbase + p;
      if (m < M) out[m] = scale * s;
    }
  }
}

extern "C" void kernel_launch(void* const* d_in, const int* in_sizes, int n_in,
                              void* d_out, int out_size, void* d_ws,
                              size_t ws_size, hipStream_t stream) {
  const float* test = (const float*)d_in[0];
  const float* train = (const float*)d_in[1];
  float* out = (float*)d_out;
  int M = in_sizes[0] / 8;
  int N = in_sizes[1] / 8;

  const double var = 0.05 * 0.05;
  const double k = 1.4426950408889634 / (2.0 * var);  // log2(e)/(2 var)
  const float negk = (float)(-k);
  const float twok = (float)(2.0 * k);
  const float coef = (float)(1.0 / sqrt(2.0 * M_PI * var));
  const float scale = coef / (float)N;

  int nblocks = (M + PTS - 1) / PTS;
  kde_fused<<<nblocks, THREADS, 0, stream>>>(test, train, out, M, N, negk,
                                             twok, scale);
}